// Round 2
// baseline (257.508 us; speedup 1.0000x reference)
//
#include <hip/hip_runtime.h>

// ---- problem constants ----
#define B_   64
#define L_   256
#define E_   1600
#define P_   100
#define KP   4
// output layout (flat float32 concat, reference return order)
#define N0 34
#define N1 33
#define N2 33
#define LOUT0 253
#define LOUT1 250
#define LOUT2 247
#define OFF_PD 0
#define OFF_D0 6400
#define OFF_D1 (OFF_D0 + B_*N0*LOUT0)   // 556928
#define OFF_D2 (OFF_D1 + B_*N1*LOUT1)   // 1084928
#define OFF_CO (OFF_D2 + B_*N2*LOUT2)   // 1606592

// ---- ws layout (fast path, bf16 pre-converted operands) ----
#define WS_ABF  0ull                          // bf16 [16384][1600]
#define WS_BT   52428800ull                   // bf16 [400][1600] (GEMM B^T)
#define WS_S    (WS_BT + 1280000ull)          // f32 [16384]
#define WS_P2   (WS_S + 65536ull)             // f32 [128]
#define WS_CNT  (WS_P2 + 512ull)              // u32 [64] per-b completion counters
#define WS_NEED (WS_CNT + 256ull)             // ~53.8 MB

// ---- main GEMM tiling (fast path): 96 rows x 80 cols, 6 waves ----
// depth-3 pipelined: K-chunk = 64B/row (32 bf16), 3 LDS buffers of 12288B
// (A 96x64 = 6KB, B 96x64 = 6KB incl. 16 pad rows for load uniformity).
// 12 staging chunks of 1KB -> exactly 2 global_load_lds per wave per phase.
#define TMF   96
#define BUF1  12288
#define NPH   50          // 3200 B/row / 64 B

typedef float f32x4 __attribute__((ext_vector_type(4)));
typedef unsigned short ushort8v __attribute__((ext_vector_type(8)));
typedef __bf16 bf16x8 __attribute__((ext_vector_type(8)));
typedef _Float16 f16;

__device__ __forceinline__ unsigned short bf16rne(float f) {
    unsigned u = __float_as_uint(f);
    u += 0x7FFFu + ((u >> 16) & 1u);
    return (unsigned short)(u >> 16);
}

typedef __attribute__((address_space(3))) void lds_void_t;
typedef __attribute__((address_space(1))) void glb_void_t;

__device__ __forceinline__ void gload16(const void* g, void* l) {
    // async global->LDS, 16B/lane; LDS dest = wave-uniform base + lane*16
    __builtin_amdgcn_global_load_lds((const glb_void_t*)g, (lds_void_t*)l, 16, 0, 0);
}

// counted waits + raw barrier (no compiler vmcnt(0) drain)
#define VWAIT4() asm volatile("s_waitcnt vmcnt(4)" ::: "memory")
#define VWAIT2() asm volatile("s_waitcnt vmcnt(2)" ::: "memory")
#define VWAIT0() asm volatile("s_waitcnt vmcnt(0)" ::: "memory")
#define SBAR()   asm volatile("s_barrier" ::: "memory")

// ===========================================================================
// FAST PATH
// ===========================================================================

// prep: emb fp32 -> bf16 ws (+ s rows); proto fp32 -> B^T bf16 ws (+ p2);
// init proto_dist to +INF; zero per-b fc completion counters
__global__ __launch_bounds__(256) void proto_prep_fast(
        const float* __restrict__ emb, const float* __restrict__ proto,
        char* __restrict__ ws, float* __restrict__ out) {
    int q = blockIdx.x;
    int wave = threadIdx.x >> 6, lane = threadIdx.x & 63;
    if (q < 4096) {                      // emb rows: one wave per (b,l) row
        int row = q * 4 + wave;          // [0,16384)
        const float4* r = (const float4*)(emb + (size_t)row * E_);
        unsigned short* dst = (unsigned short*)(ws + WS_ABF + (size_t)row * (E_*2));
        float acc = 0.f;
        #pragma unroll
        for (int it = 0; it < 6; ++it) {
            int e4 = it * 64 + lane;
            float4 v = r[e4];
            acc += v.x*v.x + v.y*v.y + v.z*v.z + v.w*v.w;
            ushort4 bv = make_ushort4(bf16rne(v.x), bf16rne(v.y),
                                      bf16rne(v.z), bf16rne(v.w));
            *(ushort4*)(dst + e4 * 4) = bv;
        }
        if (lane < 16) {
            int e4 = 384 + lane;
            float4 v = r[e4];
            acc += v.x*v.x + v.y*v.y + v.z*v.z + v.w*v.w;
            ushort4 bv = make_ushort4(bf16rne(v.x), bf16rne(v.y),
                                      bf16rne(v.z), bf16rne(v.w));
            *(ushort4*)(dst + e4 * 4) = bv;
        }
        #pragma unroll
        for (int off = 32; off; off >>= 1) acc += __shfl_down(acc, off);
        if (lane == 0) ((float*)(ws + WS_S))[row] = acc;
    } else if (q < 4121) {               // protos: one wave per proto
        int p = (q - 4096) * 4 + wave;
        if (p < P_) {
            const float4* r = (const float4*)(proto + (size_t)p * (E_ * KP));
            unsigned short* bt = (unsigned short*)(ws + WS_BT);
            float acc = 0.f;
            #pragma unroll
            for (int it = 0; it < 25; ++it) {
                int e = it * 64 + lane;
                float4 v = r[e];
                acc += v.x*v.x + v.y*v.y + v.z*v.z + v.w*v.w;
                bt[(size_t)(4*p + 0) * E_ + e] = bf16rne(v.x);
                bt[(size_t)(4*p + 1) * E_ + e] = bf16rne(v.y);
                bt[(size_t)(4*p + 2) * E_ + e] = bf16rne(v.z);
                bt[(size_t)(4*p + 3) * E_ + e] = bf16rne(v.w);
            }
            #pragma unroll
            for (int off = 32; off; off >>= 1) acc += __shfl_down(acc, off);
            if (lane == 0) ((float*)(ws + WS_P2))[p] = acc;
        }
    } else {                             // init proto_dist to +INF; zero counters
        for (int i = threadIdx.x; i < B_ * P_; i += 256)
            out[OFF_PD + i] = __uint_as_float(0x7F800000u);
        if (threadIdx.x < 64)
            ((unsigned*)(ws + WS_CNT))[threadIdx.x] = 0u;
    }
}

// main: 96x80 tile GEMM over K=1600, depth-3 counted-vmcnt pipeline.
// LDS 3x12288 = 36864 B -> 4 blocks/CU with 6 waves; grid 960 fully resident.
// Per phase per wave: 2 gload16 (issue), 6 ds_read_b128, 5 MFMA.
// vmcnt never drains to 0 in the loop (T4); raw s_barrier only.
__global__ __launch_bounds__(384, 6) void proto_main_fast(
        char* __restrict__ ws, const float* __restrict__ fc_w,
        float* __restrict__ out) {

    __shared__ __align__(64) char smem[3 * BUF1];    // 36864 B
    __shared__ int lastf;

    // XCD grouping: xcd = bx&7 (heuristic); 8 consecutive b per XCD,
    // all 15 blocks of one b on the same XCD for A/B L2 reuse
    int bx   = blockIdx.x;               // 0..959
    int lb   = (bx & 7) * 120 + (bx >> 3);
    int b     = lb / 15;
    int inner = lb % 15;
    int m     = inner / 5;
    int n_blk = inner % 5;
    int r0    = (m == 0) ? 0 : (m == 1 ? 87 : 160);
    int l_lo  = m * 87;
    int pbase = n_blk * 20;

    const char* Ag = ws + WS_ABF + (size_t)(b * L_ + r0) * (E_ * 2);
    const char* Bg = ws + WS_BT  + (size_t)(pbase * 4) * (E_ * 2);

    int tid   = threadIdx.x;
    int lane  = tid & 63;
    int wave  = tid >> 6;        // 0..5, one 16-row M-frag per wave
    int mrow  = lane & 15;
    int jq    = lane >> 4;       // 0..3 (16B K-slot within 64B row-chunk)

    // ---- staging assignment: wave w owns chunks t0=2w, t1=2w+1 of 12 ----
    // chunk t<6: A rows [t*16, +16); t>=6: B rows [(t-6)*16, +16).
    // LDS offset = t*1024 in both cases (B region starts at 6144 = 6*1024).
    // swizzle: slot s of row r holds K-seg j = s ^ (r&3); pre-swizzle source.
    int t0 = wave * 2, t1 = t0 + 1;
    int r_in = lane >> 2;                    // row within chunk
    int j16  = (((lane & 3) ^ (r_in & 3)) << 4);
    const char* q0 = (t0 < 6 ? Ag + (size_t)(t0 * 16 + r_in) * (E_*2)
                             : Bg + (size_t)((t0 - 6) * 16 + r_in) * (E_*2)) + j16;
    const char* q1 = (t1 < 6 ? Ag + (size_t)(t1 * 16 + r_in) * (E_*2)
                             : Bg + (size_t)((t1 - 6) * 16 + r_in) * (E_*2)) + j16;
    int l0 = t0 * 1024, l1 = t1 * 1024;

    // ---- read-side lane constants ----
    int sx     = ((jq ^ (mrow & 3)) << 4);           // swizzled 16B slot
    int aoff   = (wave * 16 + mrow) * 64 + sx;       // A frag addr in buffer
    int boff   = 6144 + mrow * 64 + sx;              // B frag base (ni*1024 added)

    f32x4 acc[5] = {};

    // ---- prologue: issue chunks 0,1,2 into bufs 0,1,2 (6 loads/wave) ----
    #pragma unroll
    for (int k = 0; k < 3; ++k) {
        gload16(q0, smem + k * BUF1 + l0);
        gload16(q1, smem + k * BUF1 + l1);
        q0 += 64; q1 += 64;
    }

    char* cb = smem;
    int curi = 0;

    #define COMPUTE_PHASE(CBUF)                                              \
    {                                                                        \
        ushort8v af = *(const ushort8v*)((CBUF) + aoff);                     \
        ushort8v bfv[5];                                                     \
        _Pragma("unroll")                                                    \
        for (int ni = 0; ni < 5; ++ni)                                       \
            bfv[ni] = *(const ushort8v*)((CBUF) + boff + ni * 1024);         \
        __builtin_amdgcn_s_setprio(1);                                       \
        _Pragma("unroll")                                                    \
        for (int ni = 0; ni < 5; ++ni)                                       \
            acc[ni] = __builtin_amdgcn_mfma_f32_16x16x32_bf16(               \
                __builtin_bit_cast(bf16x8, af),                              \
                __builtin_bit_cast(bf16x8, bfv[ni]),                         \
                acc[ni], 0, 0, 0);                                           \
        __builtin_amdgcn_s_setprio(0);                                       \
    }

    // ---- steady loop: phases 0..46, always issue phase c+3 ----
    for (int c = 0; c < 47; ++c) {
        VWAIT4();                // oldest chunk (c) landed; c+1, c+2 in flight
        SBAR();                  // all waves' chunk-c loads visible
        COMPUTE_PHASE(cb);
        SBAR();                  // all waves done reading buf[c%3]
        gload16(q0, cb + l0);    // issue chunk c+3 into the freed buffer
        gload16(q1, cb + l1);
        q0 += 64; q1 += 64;
        cb += BUF1; if (++curi == 3) { curi = 0; cb = smem; }
    }
    // ---- tail: phases 47,48,49 (no more issues) ----
    VWAIT4(); SBAR(); COMPUTE_PHASE(cb);
    cb += BUF1; if (++curi == 3) { curi = 0; cb = smem; }
    VWAIT2(); SBAR(); COMPUTE_PHASE(cb);
    cb += BUF1; if (++curi == 3) { curi = 0; cb = smem; }
    VWAIT0(); SBAR(); COMPUTE_PHASE(cb);

    __syncthreads();             // full sync before smem reuse by epilogue

    // ---- epilogue: Y (fp16) -> LDS, form distances ----
    f16*      Yh     = (f16*)smem;                    // [96][81]
    float*    slds   = (float*)(smem + 15552);        // [96]
    float*    p2lds  = slds + TMF;                    // [20]
    unsigned* minlds = (unsigned*)(p2lds + 20);       // [20]

    {
        int colq = lane & 15;
        int rowq = (lane >> 4) * 4;
        int row = wave * 16 + rowq;
        #pragma unroll
        for (int ni = 0; ni < 5; ++ni) {
            int col = ni * 16 + colq;
            #pragma unroll
            for (int r = 0; r < 4; ++r)
                Yh[(row + r) * 81 + col] = (f16)acc[ni][r];
        }
    }
    if (tid < TMF) slds[tid] = ((const float*)(ws + WS_S))[b * L_ + r0 + tid];
    if (tid < 20) {
        p2lds[tid] = ((const float*)(ws + WS_P2))[pbase + tid];
        minlds[tid] = 0x7F800000u;
    }
    __syncthreads();

    // l-range for this m-tile: [l_lo, l_lo+87) ∩ [0, Lout)
    for (int idx = tid; idx < 20 * 87; idx += 384) {
        int pl  = idx / 87;
        int lof = idx % 87;
        int p = pbase + pl;
        int d, Lout, nseg, pseg; size_t segbase;
        if (p < 34)      { d = 1; Lout = LOUT0; segbase = OFF_D0; pseg = p;      nseg = N0; }
        else if (p < 67) { d = 2; Lout = LOUT1; segbase = OFF_D1; pseg = p - 34; nseg = N1; }
        else             { d = 3; Lout = LOUT2; segbase = OFF_D2; pseg = p - 67; nseg = N2; }
        int l = l_lo + lof;
        if (l < Lout) {
            int rl = l - r0;
            int c0 = pl * 4;
            float xp = (float)Yh[rl * 81 + c0]
                     + (float)Yh[(rl + d) * 81 + c0 + 1]
                     + (float)Yh[(rl + 2*d) * 81 + c0 + 2]
                     + (float)Yh[(rl + 3*d) * 81 + c0 + 3];
            float x2 = slds[rl] + slds[rl + d] + slds[rl + 2*d] + slds[rl + 3*d];
            float dist = sqrtf(fabsf(x2 - 2.f * xp + p2lds[pl]));
            out[segbase + ((size_t)b * nseg + pseg) * Lout + l] = dist;
            atomicMin(&minlds[pl], __float_as_uint(dist));
        }
    }
    __syncthreads();
    if (tid < 20)
        atomicMin((unsigned*)out + OFF_PD + b * P_ + pbase + tid, minlds[tid]);

    // ---- fused fc: 15th finishing block of each b computes class_out[b,:] ----
    __syncthreads();             // drains the 20 global atomicMin
    if (tid == 0) {
        __threadfence();
        unsigned prev = atomicAdd((unsigned*)(ws + WS_CNT) + b, 1u);
        lastf = (prev == 14u);   // all 15 blocks of this b done
    }
    __syncthreads();
    if (lastf && tid < 128) {
        int cls = tid >> 6;      // wave0 -> class 0, wave1 -> class 1
        int ln  = tid & 63;
        float s = 0.f;
        for (int p = ln; p < P_; p += 64) {
            // agent-scope atomic load: bypass stale L1, read other blocks' mins
            float v = __hip_atomic_load(
                (const float*)out + OFF_PD + b * P_ + p,
                __ATOMIC_RELAXED, __HIP_MEMORY_SCOPE_AGENT);
            s += v * fc_w[cls * P_ + p];
        }
        #pragma unroll
        for (int off = 32; off; off >>= 1) s += __shfl_down(s, off);
        if (ln == 0) out[OFF_CO + b * 2 + cls] = s;
    }
    #undef COMPUTE_PHASE
}

// ===========================================================================
// FALLBACK PATH (round-1 kernels, used only if ws too small)
// ===========================================================================
#define TM   144
#define ASTR 40
#define YSTR 81

__global__ __launch_bounds__(256) void proto_prep_kernel(
        const float* __restrict__ emb, const float* __restrict__ proto,
        float* __restrict__ ws_s, float* __restrict__ ws_p2,
        float* __restrict__ out) {
    int q = blockIdx.x;
    int wave = threadIdx.x >> 6, lane = threadIdx.x & 63;
    if (q < 4096) {
        int row = q * 4 + wave;
        const float4* r = (const float4*)(emb + (size_t)row * E_);
        float acc = 0.f;
        #pragma unroll
        for (int it = 0; it < 7; ++it) {
            int e4 = it * 64 + lane;
            if (e4 < 400) {
                float4 v = r[e4];
                acc += v.x*v.x + v.y*v.y + v.z*v.z + v.w*v.w;
            }
        }
        #pragma unroll
        for (int off = 32; off; off >>= 1) acc += __shfl_down(acc, off);
        if (lane == 0) ws_s[row] = acc;
    } else if (q < 4121) {
        int p = (q - 4096) * 4 + wave;
        if (p < P_) {
            const float4* r = (const float4*)(proto + (size_t)p * (E_ * KP));
            float acc = 0.f;
            #pragma unroll
            for (int it = 0; it < 25; ++it) {
                float4 v = r[it * 64 + lane];
                acc += v.x*v.x + v.y*v.y + v.z*v.z + v.w*v.w;
            }
            #pragma unroll
            for (int off = 32; off; off >>= 1) acc += __shfl_down(acc, off);
            if (lane == 0) ws_p2[p] = acc;
        }
    } else {
        for (int i = threadIdx.x; i < B_ * P_; i += 256)
            out[OFF_PD + i] = __uint_as_float(0x7F800000u);
    }
}

__global__ __launch_bounds__(192) void proto_main_kernel(
        const float* __restrict__ emb, const float* __restrict__ proto,
        const float* __restrict__ ws_s, const float* __restrict__ ws_p2,
        float* __restrict__ out) {

    __shared__ __align__(16) char smem[47392];
    unsigned short* Ald = (unsigned short*)smem;
    unsigned short* Bld = (unsigned short*)(smem + TM*ASTR*2);

    int bx = blockIdx.x;
    int n_blk = bx % 5;
    int m     = (bx / 5) & 1;
    int b     = bx / 10;
    int r0    = m ? 112 : 0;
    int pbase = n_blk * 20;

    const float* Abase = emb + ((size_t)(b * L_ + r0)) * E_;
    const float* Bbase = proto + (size_t)pbase * (E_ * KP);

    int tid  = threadIdx.x;
    int lane = tid & 63;
    int wave = tid >> 6;
    int mrow = lane & 15;
    int kq   = (lane >> 4) * 8;

    f32x4 acc[3][5] = {};

    for (int c = 0; c < E_ / 32; ++c) {
        int e0 = c * 32;
        #pragma unroll
        for (int i = 0; i < 6; ++i) {
            int idx = tid + i * 192;
            int row = idx >> 3;
            int e4  = idx & 7;
            float4 v = *(const float4*)(Abase + (size_t)row * E_ + e0 + e4 * 4);
            ushort4 bv = make_ushort4(bf16rne(v.x), bf16rne(v.y),
                                      bf16rne(v.z), bf16rne(v.w));
            *(ushort4*)&Ald[row * ASTR + e4 * 4] = bv;
        }
        for (int idx = tid; idx < 640; idx += 192) {
            int pl = idx >> 5;
            int el = idx & 31;
            float4 v = *(const float4*)(Bbase + (size_t)pl * (E_ * KP)
                                        + (size_t)(e0 + el) * KP);
            Bld[(4*pl + 0) * ASTR + el] = bf16rne(v.x);
            Bld[(4*pl + 1) * ASTR + el] = bf16rne(v.y);
            Bld[(4*pl + 2) * ASTR + el] = bf16rne(v.z);
            Bld[(4*pl + 3) * ASTR + el] = bf16rne(v.w);
        }
        __syncthreads();

        ushort8v af[3], bfr[5];
        #pragma unroll
        for (int mi = 0; mi < 3; ++mi)
            af[mi] = *(const ushort8v*)&Ald[(wave*48 + mi*16 + mrow) * ASTR + kq];
        #pragma unroll
        for (int ni = 0; ni < 5; ++ni)
            bfr[ni] = *(const ushort8v*)&Bld[(ni*16 + mrow) * ASTR + kq];
        #pragma unroll
        for (int mi = 0; mi < 3; ++mi)
            #pragma unroll
            for (int ni = 0; ni < 5; ++ni)
                acc[mi][ni] = __builtin_amdgcn_mfma_f32_16x16x32_bf16(
                    __builtin_bit_cast(bf16x8, af[mi]),
                    __builtin_bit_cast(bf16x8, bfr[ni]),
                    acc[mi][ni], 0, 0, 0);
        __syncthreads();
    }

    float*    Ylds   = (float*)smem;
    float*    slds   = (float*)(smem + TM * YSTR * 4);
    float*    p2lds  = slds + TM;
    unsigned* minlds = (unsigned*)(p2lds + 20);

    {
        int colq = lane & 15;
        int rowq = (lane >> 4) * 4;
        #pragma unroll
        for (int mi = 0; mi < 3; ++mi) {
            int row = wave * 48 + mi * 16 + rowq;
            #pragma unroll
            for (int ni = 0; ni < 5; ++ni) {
                int col = ni * 16 + colq;
                #pragma unroll
                for (int r = 0; r < 4; ++r)
                    Ylds[(row + r) * YSTR + col] = acc[mi][ni][r];
            }
        }
    }
    if (tid < TM) slds[tid] = ws_s[b * L_ + r0 + tid];
    if (tid < 20) { p2lds[tid] = ws_p2[pbase + tid]; minlds[tid] = 0x7F800000u; }
    __syncthreads();

    int l_lo = m * 128;
    for (int idx = tid; idx < 20 * 128; idx += 192) {
        int pl  = idx >> 7;
        int lof = idx & 127;
        int p = pbase + pl;
        int d, Lout, nseg, pseg; size_t segbase;
        if (p < 34)      { d = 1; Lout = LOUT0; segbase = OFF_D0; pseg = p;      nseg = N0; }
        else if (p < 67) { d = 2; Lout = LOUT1; segbase = OFF_D1; pseg = p - 34; nseg = N1; }
        else             { d = 3; Lout = LOUT2; segbase = OFF_D2; pseg = p - 67; nseg = N2; }
        int l = l_lo + lof;
        if (l < Lout) {
            int rl = l - r0;
            int c0 = pl * 4;
            float xp = Ylds[rl * YSTR + c0]
                     + Ylds[(rl + d) * YSTR + c0 + 1]
                     + Ylds[(rl + 2*d) * YSTR + c0 + 2]
                     + Ylds[(rl + 3*d) * YSTR + c0 + 3];
            float x2 = slds[rl] + slds[rl + d] + slds[rl + 2*d] + slds[rl + 3*d];
            float dist = sqrtf(fabsf(x2 - 2.f * xp + p2lds[pl]));
            out[segbase + ((size_t)b * nseg + pseg) * Lout + l] = dist;
            atomicMin(&minlds[pl], __float_as_uint(dist));
        }
    }
    __syncthreads();
    if (tid < 20)
        atomicMin((unsigned*)out + OFF_PD + b * P_ + pbase + tid, minlds[tid]);
}

// ---------------------------------------------------------------------------
// fc (fallback path only): class_out[b,c] = sum_p proto_dist[b,p] * fc_w[c,p]
// ---------------------------------------------------------------------------
__global__ __launch_bounds__(128) void proto_fc_kernel(
        const float* __restrict__ fc_w, float* __restrict__ out) {
    int t = threadIdx.x;      // 128 = 64 b * 2 c
    int b = t >> 1, c = t & 1;
    const float* pd = out + OFF_PD + b * P_;
    const float* w  = fc_w + c * P_;
    float s = 0.f;
    #pragma unroll 4
    for (int p = 0; p < P_; ++p) s += pd[p] * w[p];
    out[OFF_CO + b * 2 + c] = s;
}

extern "C" void kernel_launch(void* const* d_in, const int* in_sizes, int n_in,
                              void* d_out, int out_size, void* d_ws, size_t ws_size,
                              hipStream_t stream) {
    const float* emb   = (const float*)d_in[0];   // [64,256,1600]
    const float* proto = (const float*)d_in[1];   // [100,1600,4]
    const float* fc_w  = (const float*)d_in[2];   // [2,100]
    float* out  = (float*)d_out;

    if (ws_size >= WS_NEED) {
        char* ws = (char*)d_ws;
        proto_prep_fast<<<4122, 256, 0, stream>>>(emb, proto, ws, out);
        proto_main_fast<<<960, 384, 0, stream>>>(ws, fc_w, out);
        // fc fused into proto_main_fast (per-b completion counters)
    } else {
        float* ws_s  = (float*)d_ws;              // 16384 floats
        float* ws_p2 = ws_s + B_ * L_;            // 100 floats
        proto_prep_kernel<<<4122, 256, 0, stream>>>(emb, proto, ws_s, ws_p2, out);
        proto_main_kernel<<<640, 192, 0, stream>>>(emb, proto, ws_s, ws_p2, out);
        proto_fc_kernel<<<1, 128, 0, stream>>>(fc_w, out);
    }
}

// Round 3
// 236.274 us; speedup vs baseline: 1.0899x; 1.0899x over previous
//
#include <hip/hip_runtime.h>

// ---- problem constants ----
#define B_   64
#define L_   256
#define E_   1600
#define P_   100
#define KP   4
// output layout (flat float32 concat, reference return order)
#define N0 34
#define N1 33
#define N2 33
#define LOUT0 253
#define LOUT1 250
#define LOUT2 247
#define OFF_PD 0
#define OFF_D0 6400
#define OFF_D1 (OFF_D0 + B_*N0*LOUT0)   // 556928
#define OFF_D2 (OFF_D1 + B_*N1*LOUT1)   // 1084928
#define OFF_CO (OFF_D2 + B_*N2*LOUT2)   // 1606592

// ---- ws layout (fast path, bf16 pre-converted operands) ----
#define WS_ABF  0ull                          // bf16 [16384][1600]
#define WS_BT   52428800ull                   // bf16 [400][1600] (GEMM B^T)
#define WS_S    (WS_BT + 1280000ull)          // f32 [16384]
#define WS_P2   (WS_S + 65536ull)             // f32 [128]
#define WS_CNT  (WS_P2 + 512ull)              // u32 [64] per-b completion counters
#define WS_NEED (WS_CNT + 256ull)             // ~53.8 MB

// ---- main GEMM tiling (fast path, v3): 144 rows x 80 cols, 3 waves ----
// Each wave owns 48 rows (3 M-frags): per K-step = 3 global A loads (reg,
// no LDS round-trip: A has zero cross-wave reuse) + 5 shared B ds_reads
// + 15 MFMA  ->  MFMA-bound (75 cyc MFMA vs 60 cyc LDS), vs the old
// 6 ds_read : 5 MFMA LDS-bound structure.
// B double-buffered in LDS (2 x 80 rows x 128 B), 8-slot XOR swizzle.
#define TMW   144
#define BBUF  10240
#define AROWB 51200       // 16 rows * 3200 B (A mi-frag row stride)

typedef float f32x4 __attribute__((ext_vector_type(4)));
typedef unsigned short ushort8v __attribute__((ext_vector_type(8)));
typedef __bf16 bf16x8 __attribute__((ext_vector_type(8)));
typedef _Float16 f16;

__device__ __forceinline__ unsigned short bf16rne(float f) {
    unsigned u = __float_as_uint(f);
    u += 0x7FFFu + ((u >> 16) & 1u);
    return (unsigned short)(u >> 16);
}

typedef __attribute__((address_space(3))) void lds_void_t;
typedef __attribute__((address_space(1))) void glb_void_t;

__device__ __forceinline__ void gload16(const void* g, void* l) {
    // async global->LDS, 16B/lane; LDS dest = wave-uniform base + lane*16
    __builtin_amdgcn_global_load_lds((const glb_void_t*)g, (lds_void_t*)l, 16, 0, 0);
}

// ===========================================================================
// FAST PATH
// ===========================================================================

// prep: emb fp32 -> bf16 ws (+ s rows); proto fp32 -> B^T bf16 ws (+ p2);
// init proto_dist to +INF; zero per-b fc completion counters
__global__ __launch_bounds__(256) void proto_prep_fast(
        const float* __restrict__ emb, const float* __restrict__ proto,
        char* __restrict__ ws, float* __restrict__ out) {
    int q = blockIdx.x;
    int wave = threadIdx.x >> 6, lane = threadIdx.x & 63;
    if (q < 4096) {                      // emb rows: one wave per (b,l) row
        int row = q * 4 + wave;          // [0,16384)
        const float4* r = (const float4*)(emb + (size_t)row * E_);
        unsigned short* dst = (unsigned short*)(ws + WS_ABF + (size_t)row * (E_*2));
        float acc = 0.f;
        #pragma unroll
        for (int it = 0; it < 6; ++it) {
            int e4 = it * 64 + lane;
            float4 v = r[e4];
            acc += v.x*v.x + v.y*v.y + v.z*v.z + v.w*v.w;
            ushort4 bv = make_ushort4(bf16rne(v.x), bf16rne(v.y),
                                      bf16rne(v.z), bf16rne(v.w));
            *(ushort4*)(dst + e4 * 4) = bv;
        }
        if (lane < 16) {
            int e4 = 384 + lane;
            float4 v = r[e4];
            acc += v.x*v.x + v.y*v.y + v.z*v.z + v.w*v.w;
            ushort4 bv = make_ushort4(bf16rne(v.x), bf16rne(v.y),
                                      bf16rne(v.z), bf16rne(v.w));
            *(ushort4*)(dst + e4 * 4) = bv;
        }
        #pragma unroll
        for (int off = 32; off; off >>= 1) acc += __shfl_down(acc, off);
        if (lane == 0) ((float*)(ws + WS_S))[row] = acc;
    } else if (q < 4121) {               // protos: one wave per proto
        int p = (q - 4096) * 4 + wave;
        if (p < P_) {
            const float4* r = (const float4*)(proto + (size_t)p * (E_ * KP));
            unsigned short* bt = (unsigned short*)(ws + WS_BT);
            float acc = 0.f;
            #pragma unroll
            for (int it = 0; it < 25; ++it) {
                int e = it * 64 + lane;
                float4 v = r[e];
                acc += v.x*v.x + v.y*v.y + v.z*v.z + v.w*v.w;
                bt[(size_t)(4*p + 0) * E_ + e] = bf16rne(v.x);
                bt[(size_t)(4*p + 1) * E_ + e] = bf16rne(v.y);
                bt[(size_t)(4*p + 2) * E_ + e] = bf16rne(v.z);
                bt[(size_t)(4*p + 3) * E_ + e] = bf16rne(v.w);
            }
            #pragma unroll
            for (int off = 32; off; off >>= 1) acc += __shfl_down(acc, off);
            if (lane == 0) ((float*)(ws + WS_P2))[p] = acc;
        }
    } else {                             // init proto_dist to +INF; zero counters
        for (int i = threadIdx.x; i < B_ * P_; i += 256)
            out[OFF_PD + i] = __uint_as_float(0x7F800000u);
        if (threadIdx.x < 64)
            ((unsigned*)(ws + WS_CNT))[threadIdx.x] = 0u;
    }
}

// main v3: 144x80 tile, 3 waves x 3 M-frags, A global->reg (prefetched),
// B LDS double-buffered (issue-early, one __syncthreads per phase).
// Grid 640 = 64 b x 2 m x 5 n; XCD swizzle 640 = 8*80 (bijective).
__global__ __launch_bounds__(192, 3) void proto_main_fast(
        char* __restrict__ ws, const float* __restrict__ fc_w,
        float* __restrict__ out) {

    __shared__ __align__(64) char smem[24576];   // B dbuf 20480 | epi 24064
    __shared__ int lastf;

    int bx = blockIdx.x;                 // 0..639
    int lb = (bx & 7) * 80 + (bx >> 3);  // all 10 blocks of one b on one XCD
    int b     = lb / 10;
    int inner = lb % 10;
    int m     = inner / 5;
    int n_blk = inner % 5;
    int r0    = m ? 112 : 0;
    int pbase = n_blk * 20;

    const char* Ag = ws + WS_ABF + (size_t)(b * L_ + r0) * (E_ * 2);
    const char* Bg = ws + WS_BT  + (size_t)(pbase * 4) * (E_ * 2);

    int tid  = threadIdx.x;
    int lane = tid & 63;
    int wave = tid >> 6;     // 0..2, owns rows [wave*48, wave*48+48)
    int mrow = lane & 15;
    int jq   = lane >> 4;    // 0..3 (16B unit within 64B K-step)

    // B staging lane constants (8 rows x 128 B per 1KB wave-chunk)
    int srow  = lane >> 3;   // row within chunk
    int sslot = lane & 7;    // stored 16B slot; source pre-swizzled

    // A per-lane base: row = wave*48 + mi*16 + mrow, 16B unit jq
    const char* Aw = Ag + (size_t)(wave * 48 + mrow) * (E_*2) + jq * 16;

    f32x4 acc[3][5] = {};
    ushort8v a_cur[3][2], a_nxt[3][2];

    // ---- prologue: stage B chunk 0 into buf0, preload A chunk 0 ----
    #pragma unroll
    for (int t0 = 0; t0 < 4; ++t0) {
        int t = wave + t0 * 3;
        if (t < 10) {
            int row = t * 8 + srow;
            gload16(Bg + (size_t)row * (E_*2) + ((sslot ^ (row & 7)) << 4),
                    smem + t * 1024);
        }
    }
    #pragma unroll
    for (int mi = 0; mi < 3; ++mi)
        #pragma unroll
        for (int ks = 0; ks < 2; ++ks)
            a_cur[mi][ks] = *(const ushort8v*)(Aw + mi * AROWB + ks * 64);
    __syncthreads();

    for (int c = 0; c < 25; ++c) {
        const char* cbuf = smem + (c & 1) * BBUF;
        char* nbuf = (char*)smem + ((c + 1) & 1) * BBUF;
        if (c < 24) {
            int eoff = (c + 1) * 128;
            // issue next B chunk (async LDS) + prefetch next A frags (regs)
            #pragma unroll
            for (int t0 = 0; t0 < 4; ++t0) {
                int t = wave + t0 * 3;
                if (t < 10) {
                    int row = t * 8 + srow;
                    gload16(Bg + (size_t)row * (E_*2) + eoff
                              + ((sslot ^ (row & 7)) << 4),
                            nbuf + t * 1024);
                }
            }
            #pragma unroll
            for (int mi = 0; mi < 3; ++mi)
                #pragma unroll
                for (int ks = 0; ks < 2; ++ks)
                    a_nxt[mi][ks] = *(const ushort8v*)(Aw + eoff
                                        + mi * AROWB + ks * 64);
        }
        // ---- compute chunk c: 2 K-steps x (5 B ds_reads + 15 MFMA) ----
        #pragma unroll
        for (int ks = 0; ks < 2; ++ks) {
            ushort8v bfv[5];
            #pragma unroll
            for (int ni = 0; ni < 5; ++ni) {
                int rowB = ni * 16 + mrow;
                bfv[ni] = *(const ushort8v*)(cbuf + rowB * 128
                            + ((((ks << 2) + jq) ^ (rowB & 7)) << 4));
            }
            __builtin_amdgcn_s_setprio(1);
            #pragma unroll
            for (int mi = 0; mi < 3; ++mi)
                #pragma unroll
                for (int ni = 0; ni < 5; ++ni)
                    acc[mi][ni] = __builtin_amdgcn_mfma_f32_16x16x32_bf16(
                        __builtin_bit_cast(bf16x8, a_cur[mi][ks]),
                        __builtin_bit_cast(bf16x8, bfv[ni]),
                        acc[mi][ni], 0, 0, 0);
            __builtin_amdgcn_s_setprio(0);
        }
        // one barrier: drains my stage loads + a_nxt (vmcnt0) AND ensures
        // all waves finished reading cbuf before it's overwritten at c+1
        __syncthreads();
        if (c < 24) {
            #pragma unroll
            for (int mi = 0; mi < 3; ++mi)
                #pragma unroll
                for (int ks = 0; ks < 2; ++ks)
                    a_cur[mi][ks] = a_nxt[mi][ks];
        }
    }

    // ---- epilogue: Y (fp16) -> LDS, form distances ----
    f16*      Yh     = (f16*)smem;                    // [144][81] = 23328 B
    float*    slds   = (float*)(smem + 23328);        // [144]
    float*    p2lds  = slds + TMW;                    // [20]
    unsigned* minlds = (unsigned*)(p2lds + 20);       // [20]

    {
        int colq = lane & 15;
        int rowq = (lane >> 4) * 4;
        #pragma unroll
        for (int mi = 0; mi < 3; ++mi) {
            int row = wave * 48 + mi * 16 + rowq;
            #pragma unroll
            for (int ni = 0; ni < 5; ++ni) {
                int col = ni * 16 + colq;
                #pragma unroll
                for (int r = 0; r < 4; ++r)
                    Yh[(row + r) * 81 + col] = (f16)acc[mi][ni][r];
            }
        }
    }
    if (tid < TMW) slds[tid] = ((const float*)(ws + WS_S))[b * L_ + r0 + tid];
    if (tid < 20) {
        p2lds[tid] = ((const float*)(ws + WS_P2))[pbase + tid];
        minlds[tid] = 0x7F800000u;
    }
    __syncthreads();

    // l-range for this m-tile: m=0 -> [0,128), m=1 -> [128, Lout)
    int l_lo = m * 128;
    for (int idx = tid; idx < 20 * 128; idx += 192) {
        int pl  = idx >> 7;
        int lof = idx & 127;
        int p = pbase + pl;
        int d, Lout, nseg, pseg; size_t segbase;
        if (p < 34)      { d = 1; Lout = LOUT0; segbase = OFF_D0; pseg = p;      nseg = N0; }
        else if (p < 67) { d = 2; Lout = LOUT1; segbase = OFF_D1; pseg = p - 34; nseg = N1; }
        else             { d = 3; Lout = LOUT2; segbase = OFF_D2; pseg = p - 67; nseg = N2; }
        int l = l_lo + lof;
        if (l < Lout) {
            int rl = l - r0;
            int c0 = pl * 4;
            float xp = (float)Yh[rl * 81 + c0]
                     + (float)Yh[(rl + d) * 81 + c0 + 1]
                     + (float)Yh[(rl + 2*d) * 81 + c0 + 2]
                     + (float)Yh[(rl + 3*d) * 81 + c0 + 3];
            float x2 = slds[rl] + slds[rl + d] + slds[rl + 2*d] + slds[rl + 3*d];
            float dist = sqrtf(fabsf(x2 - 2.f * xp + p2lds[pl]));
            out[segbase + ((size_t)b * nseg + pseg) * Lout + l] = dist;
            atomicMin(&minlds[pl], __float_as_uint(dist));
        }
    }
    __syncthreads();
    if (tid < 20)
        atomicMin((unsigned*)out + OFF_PD + b * P_ + pbase + tid, minlds[tid]);

    // ---- fused fc: 10th finishing block of each b computes class_out[b,:] ----
    __syncthreads();             // drains the 20 global atomicMin
    if (tid == 0) {
        __threadfence();
        unsigned prev = atomicAdd((unsigned*)(ws + WS_CNT) + b, 1u);
        lastf = (prev == 9u);    // all 10 blocks of this b done
    }
    __syncthreads();
    if (lastf && tid < 128) {
        int cls = tid >> 6;      // wave0 -> class 0, wave1 -> class 1
        int ln  = tid & 63;
        float s = 0.f;
        for (int p = ln; p < P_; p += 64) {
            // agent-scope atomic load: bypass stale L1, read other blocks' mins
            float v = __hip_atomic_load(
                (const float*)out + OFF_PD + b * P_ + p,
                __ATOMIC_RELAXED, __HIP_MEMORY_SCOPE_AGENT);
            s += v * fc_w[cls * P_ + p];
        }
        #pragma unroll
        for (int off = 32; off; off >>= 1) s += __shfl_down(s, off);
        if (ln == 0) out[OFF_CO + b * 2 + cls] = s;
    }
}

// ===========================================================================
// FALLBACK PATH (round-1 kernels, used only if ws too small)
// ===========================================================================
#define TM   144
#define ASTR 40
#define YSTR 81

__global__ __launch_bounds__(256) void proto_prep_kernel(
        const float* __restrict__ emb, const float* __restrict__ proto,
        float* __restrict__ ws_s, float* __restrict__ ws_p2,
        float* __restrict__ out) {
    int q = blockIdx.x;
    int wave = threadIdx.x >> 6, lane = threadIdx.x & 63;
    if (q < 4096) {
        int row = q * 4 + wave;
        const float4* r = (const float4*)(emb + (size_t)row * E_);
        float acc = 0.f;
        #pragma unroll
        for (int it = 0; it < 7; ++it) {
            int e4 = it * 64 + lane;
            if (e4 < 400) {
                float4 v = r[e4];
                acc += v.x*v.x + v.y*v.y + v.z*v.z + v.w*v.w;
            }
        }
        #pragma unroll
        for (int off = 32; off; off >>= 1) acc += __shfl_down(acc, off);
        if (lane == 0) ws_s[row] = acc;
    } else if (q < 4121) {
        int p = (q - 4096) * 4 + wave;
        if (p < P_) {
            const float4* r = (const float4*)(proto + (size_t)p * (E_ * KP));
            float acc = 0.f;
            #pragma unroll
            for (int it = 0; it < 25; ++it) {
                float4 v = r[it * 64 + lane];
                acc += v.x*v.x + v.y*v.y + v.z*v.z + v.w*v.w;
            }
            #pragma unroll
            for (int off = 32; off; off >>= 1) acc += __shfl_down(acc, off);
            if (lane == 0) ws_p2[p] = acc;
        }
    } else {
        for (int i = threadIdx.x; i < B_ * P_; i += 256)
            out[OFF_PD + i] = __uint_as_float(0x7F800000u);
    }
}

__global__ __launch_bounds__(192) void proto_main_kernel(
        const float* __restrict__ emb, const float* __restrict__ proto,
        const float* __restrict__ ws_s, const float* __restrict__ ws_p2,
        float* __restrict__ out) {

    __shared__ __align__(16) char smem[47392];
    unsigned short* Ald = (unsigned short*)smem;
    unsigned short* Bld = (unsigned short*)(smem + TM*ASTR*2);

    int bx = blockIdx.x;
    int n_blk = bx % 5;
    int m     = (bx / 5) & 1;
    int b     = bx / 10;
    int r0    = m ? 112 : 0;
    int pbase = n_blk * 20;

    const float* Abase = emb + ((size_t)(b * L_ + r0)) * E_;
    const float* Bbase = proto + (size_t)pbase * (E_ * KP);

    int tid  = threadIdx.x;
    int lane = tid & 63;
    int wave = tid >> 6;
    int mrow = lane & 15;
    int kq   = (lane >> 4) * 8;

    f32x4 acc[3][5] = {};

    for (int c = 0; c < E_ / 32; ++c) {
        int e0 = c * 32;
        #pragma unroll
        for (int i = 0; i < 6; ++i) {
            int idx = tid + i * 192;
            int row = idx >> 3;
            int e4  = idx & 7;
            float4 v = *(const float4*)(Abase + (size_t)row * E_ + e0 + e4 * 4);
            ushort4 bv = make_ushort4(bf16rne(v.x), bf16rne(v.y),
                                      bf16rne(v.z), bf16rne(v.w));
            *(ushort4*)&Ald[row * ASTR + e4 * 4] = bv;
        }
        for (int idx = tid; idx < 640; idx += 192) {
            int pl = idx >> 5;
            int el = idx & 31;
            float4 v = *(const float4*)(Bbase + (size_t)pl * (E_ * KP)
                                        + (size_t)(e0 + el) * KP);
            Bld[(4*pl + 0) * ASTR + el] = bf16rne(v.x);
            Bld[(4*pl + 1) * ASTR + el] = bf16rne(v.y);
            Bld[(4*pl + 2) * ASTR + el] = bf16rne(v.z);
            Bld[(4*pl + 3) * ASTR + el] = bf16rne(v.w);
        }
        __syncthreads();

        ushort8v af[3], bfr[5];
        #pragma unroll
        for (int mi = 0; mi < 3; ++mi)
            af[mi] = *(const ushort8v*)&Ald[(wave*48 + mi*16 + mrow) * ASTR + kq];
        #pragma unroll
        for (int ni = 0; ni < 5; ++ni)
            bfr[ni] = *(const ushort8v*)&Bld[(ni*16 + mrow) * ASTR + kq];
        #pragma unroll
        for (int mi = 0; mi < 3; ++mi)
            #pragma unroll
            for (int ni = 0; ni < 5; ++ni)
                acc[mi][ni] = __builtin_amdgcn_mfma_f32_16x16x32_bf16(
                    __builtin_bit_cast(bf16x8, af[mi]),
                    __builtin_bit_cast(bf16x8, bfr[ni]),
                    acc[mi][ni], 0, 0, 0);
        __syncthreads();
    }

    float*    Ylds   = (float*)smem;
    float*    slds   = (float*)(smem + TM * YSTR * 4);
    float*    p2lds  = slds + TM;
    unsigned* minlds = (unsigned*)(p2lds + 20);

    {
        int colq = lane & 15;
        int rowq = (lane >> 4) * 4;
        #pragma unroll
        for (int mi = 0; mi < 3; ++mi) {
            int row = wave * 48 + mi * 16 + rowq;
            #pragma unroll
            for (int ni = 0; ni < 5; ++ni) {
                int col = ni * 16 + colq;
                #pragma unroll
                for (int r = 0; r < 4; ++r)
                    Ylds[(row + r) * YSTR + col] = acc[mi][ni][r];
            }
        }
    }
    if (tid < TM) slds[tid] = ws_s[b * L_ + r0 + tid];
    if (tid < 20) { p2lds[tid] = ws_p2[pbase + tid]; minlds[tid] = 0x7F800000u; }
    __syncthreads();

    int l_lo = m * 128;
    for (int idx = tid; idx < 20 * 128; idx += 192) {
        int pl  = idx >> 7;
        int lof = idx & 127;
        int p = pbase + pl;
        int d, Lout, nseg, pseg; size_t segbase;
        if (p < 34)      { d = 1; Lout = LOUT0; segbase = OFF_D0; pseg = p;      nseg = N0; }
        else if (p < 67) { d = 2; Lout = LOUT1; segbase = OFF_D1; pseg = p - 34; nseg = N1; }
        else             { d = 3; Lout = LOUT2; segbase = OFF_D2; pseg = p - 67; nseg = N2; }
        int l = l_lo + lof;
        if (l < Lout) {
            int rl = l - r0;
            int c0 = pl * 4;
            float xp = Ylds[rl * YSTR + c0]
                     + Ylds[(rl + d) * YSTR + c0 + 1]
                     + Ylds[(rl + 2*d) * YSTR + c0 + 2]
                     + Ylds[(rl + 3*d) * YSTR + c0 + 3];
            float x2 = slds[rl] + slds[rl + d] + slds[rl + 2*d] + slds[rl + 3*d];
            float dist = sqrtf(fabsf(x2 - 2.f * xp + p2lds[pl]));
            out[segbase + ((size_t)b * nseg + pseg) * Lout + l] = dist;
            atomicMin(&minlds[pl], __float_as_uint(dist));
        }
    }
    __syncthreads();
    if (tid < 20)
        atomicMin((unsigned*)out + OFF_PD + b * P_ + pbase + tid, minlds[tid]);
}

// ---------------------------------------------------------------------------
// fc (fallback path only): class_out[b,c] = sum_p proto_dist[b,p] * fc_w[c,p]
// ---------------------------------------------------------------------------
__global__ __launch_bounds__(128) void proto_fc_kernel(
        const float* __restrict__ fc_w, float* __restrict__ out) {
    int t = threadIdx.x;      // 128 = 64 b * 2 c
    int b = t >> 1, c = t & 1;
    const float* pd = out + OFF_PD + b * P_;
    const float* w  = fc_w + c * P_;
    float s = 0.f;
    #pragma unroll 4
    for (int p = 0; p < P_; ++p) s += pd[p] * w[p];
    out[OFF_CO + b * 2 + c] = s;
}

extern "C" void kernel_launch(void* const* d_in, const int* in_sizes, int n_in,
                              void* d_out, int out_size, void* d_ws, size_t ws_size,
                              hipStream_t stream) {
    const float* emb   = (const float*)d_in[0];   // [64,256,1600]
    const float* proto = (const float*)d_in[1];   // [100,1600,4]
    const float* fc_w  = (const float*)d_in[2];   // [2,100]
    float* out  = (float*)d_out;

    if (ws_size >= WS_NEED) {
        char* ws = (char*)d_ws;
        proto_prep_fast<<<4122, 256, 0, stream>>>(emb, proto, ws, out);
        proto_main_fast<<<640, 192, 0, stream>>>(ws, fc_w, out);
        // fc fused into proto_main_fast (per-b completion counters)
    } else {
        float* ws_s  = (float*)d_ws;              // 16384 floats
        float* ws_p2 = ws_s + B_ * L_;            // 100 floats
        proto_prep_kernel<<<4122, 256, 0, stream>>>(emb, proto, ws_s, ws_p2, out);
        proto_main_kernel<<<640, 192, 0, stream>>>(emb, proto, ws_s, ws_p2, out);
        proto_fc_kernel<<<1, 128, 0, stream>>>(fc_w, out);
    }
}